// Round 7
// baseline (5589.769 us; speedup 1.0000x reference)
//
#include <hip/hip_runtime.h>

// HSMM forward log-likelihood, B=32, T=8192, K=128, Dmax=128.
// One block per sequence (32 blocks, 512 threads = 8 waves).
// Probability-space recursion, per-state gauge psi (write-once ring slots),
// 1-step-delayed global-max renorm (deadbeat/stable; 2-step = undamped
// oscillator -> NaN, learned R2-R4).
//
// R7: LDS-traffic redesign (R1/R5/R6 all ~5.4ms with identical LDS pattern
// -> LDS-pipe-bound). Matvec decomposition 8 sources x 4 dests per thread:
//   lane L, wave w:  sg = L&15 (source seg), row = L>>4, dg = row + 4w,
//   dests [4dg,4dg+4), ring-state j = 4dg + ((L&15)>>2), ring quarter q=L&3.
// s-read: 2 b128/lane of OWN segment (skewed stride-36, 2-way banks) vs 8
// broadcast b128 before. Dest sum = 16-lane DPP reduce (xor1,xor2,mirror7,
// mirror15). mv[j] -> ring lanes via 3 cndmask. Duration ring/e-window/gauge
// = R6 verbatim (c->q). expD table bank-skewed: col (j + 8*(d>>5))&127.

#define T_LEN 8192
#define KST   128
#define NTHR  512
#define SSTR  36                 // skewed s segment stride (floats), 144B: 16B-aligned, 2-way banks
#define SROW  (16 * SSTR)        // 576 floats per s buffer

__device__ __forceinline__ void barrier_nodrain() {
  // LDS producer->consumer needs lgkmcnt(0)+barrier only; global prefetch
  // loads (vmcnt) stay in flight across the barrier.
  asm volatile("s_waitcnt lgkmcnt(0)\n\ts_barrier" ::: "memory");
}

// DPP move: result = src permuted by CTRL; invalid lanes -> 0 (bound_ctrl).
template <int CTRL>
__device__ __forceinline__ float dpp_mov(float x) {
  int y = __builtin_amdgcn_update_dpp(0, __builtin_bit_cast(int, x),
                                      CTRL, 0xF, 0xF, true);
  return __builtin_bit_cast(float, y);
}
template <int CTRL>
__device__ __forceinline__ float dpp_add(float x) { return x + dpp_mov<CTRL>(x); }

template <int U>
__device__ __forceinline__ void step_body(
    int t0, int q, int jj, int w, int L, int sg,
    const float* __restrict__ pB,
    float (&QA)[16], float (&QB)[16],
    const float (&a)[4][8],
    float (&eA)[16], float (&eB)[16],
    float (&lb)[16],
    float& psi, float& invpsi, float& exq, float& Ctot, float& s_keep,
    float expD0, float pexp, int saddr, int rsel,
    float (*s_lds)[SROW], float (*m_lds)[8],
    const float (*expD_x)[KST])
{
  const int t = t0 + U;
  const float expB = exq;   // exp(logB[t,j]) computed last step (off-path)

  // (a) prefetch logB t+16 (stays in flight across barriers)
  int tn = t + 16; tn = (tn < T_LEN) ? tn : (T_LEN - 1);
  lb[U] = pB[(size_t)tn * KST];

  // (b) expD rotation reads for NEXT step (skewed table, temps)
  const int rowA = (t + 1 - 32 * q) & 127;
  const int rowB = (rowA - 16) & 127;
  const float neA = expD_x[rowA][(jj + 8 * (rowA >> 5)) & 127];
  const float neB = expD_x[rowB][(jj + 8 * (rowB >> 5)) & 127];

  // (c) previous step's wave maxes (uniform b128 reads)
  const float4 mm0 = *(const float4*)&m_lds[U & 1][0];
  const float4 mm1 = *(const float4*)&m_lds[U & 1][4];

  // (d) shat(t-1): OWN 8-float segment (2 b128, skewed, 2-way banks)
  const float* sp = &s_lds[U & 1][SSTR * sg];
  const float4 v0 = *(const float4*)(sp + 0);
  const float4 v1 = *(const float4*)(sp + 4);

  // (e) duration dot: register-only 4-acc trees (overlaps LDS latency)
  float d0 = 0.f, d1 = 0.f, d2 = 0.f, d3 = 0.f;
#pragma unroll
  for (int k = 0; k < 8; ++k) {
    d0 = fmaf(QA[k],     eA[(k - U) & 15],     d0);
    d1 = fmaf(QA[k + 8], eA[(k + 8 - U) & 15], d1);
    d2 = fmaf(QB[k],     eB[(k - U) & 15],     d2);
    d3 = fmaf(QB[k + 8], eB[(k + 8 - U) & 15], d3);
  }
  float dp = (d0 + d1) + (d2 + d3);

  // (f) gauge: Mp from step t-1 (clamp = exact free gauge + NaN firewall)
  float Mp = fmaxf(fmaxf(fmaxf(mm0.x, mm0.y), fmaxf(mm0.z, mm0.w)),
                   fmaxf(fmaxf(mm1.x, mm1.y), fmaxf(mm1.z, mm1.w)));
  Mp = fminf(fmaxf(Mp, 1e-30f), 1e30f);
  const float rMp = __builtin_amdgcn_rcpf(Mp);
  Ctot += __logf(Mp);
  psi = psi * expB * rMp;

  // (g) matvec partials: 4 dests x own 8 sources
  float c0 = 0.f, c1 = 0.f, c2 = 0.f, c3 = 0.f;
  c0 = fmaf(a[0][0], v0.x, c0); c0 = fmaf(a[0][1], v0.y, c0);
  c0 = fmaf(a[0][2], v0.z, c0); c0 = fmaf(a[0][3], v0.w, c0);
  c0 = fmaf(a[0][4], v1.x, c0); c0 = fmaf(a[0][5], v1.y, c0);
  c0 = fmaf(a[0][6], v1.z, c0); c0 = fmaf(a[0][7], v1.w, c0);
  c1 = fmaf(a[1][0], v0.x, c1); c1 = fmaf(a[1][1], v0.y, c1);
  c1 = fmaf(a[1][2], v0.z, c1); c1 = fmaf(a[1][3], v0.w, c1);
  c1 = fmaf(a[1][4], v1.x, c1); c1 = fmaf(a[1][5], v1.y, c1);
  c1 = fmaf(a[1][6], v1.z, c1); c1 = fmaf(a[1][7], v1.w, c1);
  c2 = fmaf(a[2][0], v0.x, c2); c2 = fmaf(a[2][1], v0.y, c2);
  c2 = fmaf(a[2][2], v0.z, c2); c2 = fmaf(a[2][3], v0.w, c2);
  c2 = fmaf(a[2][4], v1.x, c2); c2 = fmaf(a[2][5], v1.y, c2);
  c2 = fmaf(a[2][6], v1.z, c2); c2 = fmaf(a[2][7], v1.w, c2);
  c3 = fmaf(a[3][0], v0.x, c3); c3 = fmaf(a[3][1], v0.y, c3);
  c3 = fmaf(a[3][2], v0.z, c3); c3 = fmaf(a[3][3], v0.w, c3);
  c3 = fmaf(a[3][4], v1.x, c3); c3 = fmaf(a[3][5], v1.y, c3);
  c3 = fmaf(a[3][6], v1.z, c3); c3 = fmaf(a[3][7], v1.w, c3);

  // (h) 16-lane row sum (over sg): xor1, xor2, mirror7, mirror15
  c0 = dpp_add<0xB1>(c0); c0 = dpp_add<0x4E>(c0);
  c0 = dpp_add<0x141>(c0); c0 = dpp_add<0x140>(c0);
  c1 = dpp_add<0xB1>(c1); c1 = dpp_add<0x4E>(c1);
  c1 = dpp_add<0x141>(c1); c1 = dpp_add<0x140>(c1);
  c2 = dpp_add<0xB1>(c2); c2 = dpp_add<0x4E>(c2);
  c2 = dpp_add<0x141>(c2); c2 = dpp_add<0x140>(c2);
  c3 = dpp_add<0xB1>(c3); c3 = dpp_add<0x4E>(c3);
  c3 = dpp_add<0x141>(c3); c3 = dpp_add<0x140>(c3);

  // (i) select this lane's ring-state mv: rsel = (L&15)>>2
  float mvj = (rsel == 0) ? c0 : (rsel == 1) ? c1 : (rsel == 2) ? c2 : c3;

  // (j) dp: sum the 4 ring quarters of state j (quad lanes)
  dp = dpp_add<0xB1>(dp); dp = dpp_add<0x4E>(dp);

  // (k) insert value (M factors cancel exactly); s_hat (quad-uniform)
  const float Qins = (t == 0) ? pexp : mvj * invpsi;
  const float s = fmaf(Qins, expD0, dp) * psi;

  // (l) exp for NEXT step (value loaded 15 steps ago -> arrived)
  exq = __expf(lb[(U + 1) & 15]);

  // (m) ring insert: slot p = t&127 -> quarter (t>>5)&3, half bit4, reg U
  if (((t >> 5) & 3) == q) {
    if ((t >> 4) & 1) QB[U] = Qins; else QA[U] = Qins;
  }

  // (n) wave max over 16 states (s quad-uniform; values >= 0 so zero-fill
  //     of bcast15/31 is harmless under fmax); lane 63 holds wave max
  float sm = fmaxf(s, dpp_mov<0x141>(s));
  sm = fmaxf(sm, dpp_mov<0x140>(sm));
  sm = fmaxf(sm, dpp_mov<0x142>(sm));
  sm = fmaxf(sm, dpp_mov<0x143>(sm));
  if (L == 63) m_lds[(U + 1) & 1][w] = sm;

  // (o) publish shat: one lane per state (q==0), skewed segment layout
  if (q == 0) s_lds[(U + 1) & 1][saddr] = s;

  // (p) commit expD window rotation (old values fully consumed in (e))
  eA[(15 - U) & 15] = neA;
  eB[(15 - U) & 15] = neB;

  // (q) gauge renorm every 16 steps: fold psi into ring, reset
  if (U == 15) {
#pragma unroll
    for (int k = 0; k < 16; ++k) { QA[k] *= psi; QB[k] *= psi; }
    psi = 1.0f;
  }

  // (r) 1/psi for next step (off-path here)
  invpsi = __builtin_amdgcn_rcpf(psi);

  s_keep = s;
  barrier_nodrain();
}

__global__ __launch_bounds__(NTHR, 1) void hsmm_fwd_kernel(
    const float* __restrict__ logB_all,
    const float* __restrict__ logpi,
    const float* __restrict__ logA,
    const float* __restrict__ logD,
    float* __restrict__ out)
{
  const int tid = threadIdx.x;
  const int L   = tid & 63;
  const int w   = tid >> 6;
  const int q   = L & 3;                 // ring quarter (quad lanes)
  const int sg  = L & 15;                // matvec source segment
  const int row = L >> 4;                // 0..3
  const int dg  = row + 4 * w;           // dest group: dests [4dg, 4dg+4)
  const int rsel = (L >> 2) & 3;         // dest index within group
  const int jj  = 4 * dg + rsel;         // owned ring state
  const int b   = blockIdx.x;
  const float* __restrict__ pB = logB_all + (size_t)b * T_LEN * KST + jj;

  __shared__ __align__(16) float expD_x[128][KST];  // skewed: [d][(j+8*(d>>5))&127]
  __shared__ __align__(16) float s_lds[2][SROW];    // shat, 16 segs x stride 36
  __shared__ __align__(16) float m_lds[2][8];       // wave maxes, dbuf
  __shared__ __align__(16) float fin[8];

  // ---- init: skewed expD table (row 0 zeroed = stale-slot kill) ----
  for (int idx = tid; idx < 128 * KST; idx += NTHR) {
    int d = idx >> 7, j0 = idx & 127;
    float v = (d == 0) ? 0.0f : __expf(logD[j0 * 128 + d]);
    expD_x[d][(j0 + 8 * (d >> 5)) & 127] = v;
  }
  for (int idx = tid; idx < 2 * SROW; idx += NTHR) (&s_lds[0][0])[idx] = 0.0f;
  if (tid < 16) m_lds[tid >> 3][tid & 7] = 1.0f;

  // ---- matvec constants: A[8 sources of sg][4 dests of dg] ----
  float a[4][8];
#pragma unroll
  for (int r = 0; r < 4; ++r)
#pragma unroll
    for (int k = 0; k < 8; ++k)
      a[r][k] = __expf(logA[(8 * sg + k) * KST + (4 * dg + r)]);

  const float expD0 = __expf(logD[jj * 128 + 0]);
  const float pexp  = __expf(logpi[jj]);
  const int   jo    = jj & 15;                       // j = 16w + jo
  const int   saddr = SSTR * ((jj >> 3)) + (jj & 7); // skewed write addr
  (void)jo;

  float QA[16], QB[16];
#pragma unroll
  for (int k = 0; k < 16; ++k) { QA[k] = 0.0f; QB[k] = 0.0f; }

  __syncthreads();  // table + buffers ready (full drain once is fine)

  // e-window init for t=0: eA[k] = expD[(-(32q+k))&127] of state jj (skewed)
  float eA[16], eB[16];
#pragma unroll
  for (int k = 0; k < 16; ++k) {
    int rA = (-(32 * q + k)) & 127;
    int rB = (-(32 * q + 16 + k)) & 127;
    eA[k] = expD_x[rA][(jj + 8 * (rA >> 5)) & 127];
    eB[k] = expD_x[rB][(jj + 8 * (rB >> 5)) & 127];
  }

  // log_B prefetch ring (16 ahead)
  float lb[16];
#pragma unroll
  for (int u = 0; u < 16; ++u) lb[u] = pB[(size_t)u * KST];

  float psi    = 1.0f;
  float invpsi = 1.0f;
  float Ctot   = 0.0f;
  float s_keep = 0.0f;
  float exq    = __expf(lb[0]);

#pragma unroll 1
  for (int t0 = 0; t0 < T_LEN; t0 += 16) {
#define STEP(U) step_body<U>(t0, q, jj, w, L, sg, pB, QA, QB, a, eA, eB, lb,  \
                             psi, invpsi, exq, Ctot, s_keep, expD0, pexp,     \
                             saddr, rsel, s_lds, m_lds, expD_x)
    STEP(0);  STEP(1);  STEP(2);  STEP(3);
    STEP(4);  STEP(5);  STEP(6);  STEP(7);
    STEP(8);  STEP(9);  STEP(10); STEP(11);
    STEP(12); STEP(13); STEP(14); STEP(15);
#undef STEP
  }

  // ---- final: out[b] = Ctot + log sum_j shat[j] (each state once: q==0) ---
  float v = (q == 0) ? s_keep : 0.0f;
  v += __shfl_xor(v, 4);  v += __shfl_xor(v, 8);
  v += __shfl_xor(v, 16); v += __shfl_xor(v, 32);
  if (L == 0) fin[w] = v;
  __syncthreads();
  if (tid == 0) {
    float tot = 0.0f;
#pragma unroll
    for (int i = 0; i < 8; ++i) tot += fin[i];
    out[b] = Ctot + __logf(tot);
  }
}

extern "C" void kernel_launch(void* const* d_in, const int* in_sizes, int n_in,
                              void* d_out, int out_size, void* d_ws, size_t ws_size,
                              hipStream_t stream) {
  const float* logB  = (const float*)d_in[0];
  const float* logpi = (const float*)d_in[1];
  const float* logA  = (const float*)d_in[2];
  const float* logD  = (const float*)d_in[3];
  float* out = (float*)d_out;
  const int B = out_size;  // 32
  hipLaunchKernelGGL(hsmm_fwd_kernel, dim3(B), dim3(NTHR), 0, stream,
                     logB, logpi, logA, logD, out);
}